// Round 1
// baseline (2967.287 us; speedup 1.0000x reference)
//
#include <hip/hip_runtime.h>

#define N_NODES 100000
#define EMB 128
#define NE 800000   // edges per edge set (pos / neg)

// ---------------- degree / dinv ----------------

__global__ void zero_f32_kernel(float* __restrict__ p, int n) {
    int i = blockIdx.x * blockDim.x + threadIdx.x;
    if (i < n) p[i] = 0.0f;
}

__global__ void deg_kernel(const int* __restrict__ pos_dst,
                           const int* __restrict__ neg_dst,
                           float* __restrict__ deg) {
    int i = blockIdx.x * blockDim.x + threadIdx.x;
    if (i < 2 * NE) {
        int d = (i < NE) ? pos_dst[i] : neg_dst[i - NE];
        atomicAdd(&deg[d], 1.0f);
    }
}

__global__ void dinv_kernel(float* __restrict__ deg) {
    int i = blockIdx.x * blockDim.x + threadIdx.x;
    if (i < N_NODES) {
        deg[i] = rsqrtf(deg[i] + 1.0f);   // +1 self-loop; deg >= 1 so no div-by-0
    }
}

// ---------------- GEMM: H = X @ W  (X: [N,128], W: [128,128]) ----------------
// 32 rows per block, 256 threads, W staged in LDS, 4x4 register blocking.

#define TR 32

__global__ __launch_bounds__(256) void gemm_kernel(const float* __restrict__ X,
                                                   const float* __restrict__ W,
                                                   float* __restrict__ H) {
    __shared__ float Wl[128 * 128];      // 64 KiB, [k][c]
    __shared__ float Xt[128][TR + 1];    // transposed x tile, [k][r], ~16.9 KiB

    const int tid  = threadIdx.x;
    const int row0 = blockIdx.x * TR;

    // stage W: 16384 floats, float4-coalesced
    for (int i = tid * 4; i < 128 * 128; i += 256 * 4) {
        *(float4*)&Wl[i] = *(const float4*)&W[i];
    }
    // stage X tile transposed: TR*128 floats = 1024 float4
    for (int i = tid; i < TR * 128 / 4; i += 256) {
        int r  = i / 32;
        int k4 = (i % 32) * 4;
        float4 v = *(const float4*)&X[(size_t)(row0 + r) * EMB + k4];
        Xt[k4 + 0][r] = v.x;
        Xt[k4 + 1][r] = v.y;
        Xt[k4 + 2][r] = v.z;
        Xt[k4 + 3][r] = v.w;
    }
    __syncthreads();

    const int c0 = (tid % 32) * 4;   // output col group
    const int r0 = (tid / 32) * 4;   // output row group (within tile)

    float acc[4][4];
#pragma unroll
    for (int i = 0; i < 4; ++i)
#pragma unroll
        for (int j = 0; j < 4; ++j) acc[i][j] = 0.0f;

#pragma unroll 8
    for (int k = 0; k < 128; ++k) {
        float4 b = *(float4*)&Wl[k * 128 + c0];
        float a0 = Xt[k][r0 + 0];
        float a1 = Xt[k][r0 + 1];
        float a2 = Xt[k][r0 + 2];
        float a3 = Xt[k][r0 + 3];
        acc[0][0] += a0 * b.x; acc[0][1] += a0 * b.y; acc[0][2] += a0 * b.z; acc[0][3] += a0 * b.w;
        acc[1][0] += a1 * b.x; acc[1][1] += a1 * b.y; acc[1][2] += a1 * b.z; acc[1][3] += a1 * b.w;
        acc[2][0] += a2 * b.x; acc[2][1] += a2 * b.y; acc[2][2] += a2 * b.z; acc[2][3] += a2 * b.w;
        acc[3][0] += a3 * b.x; acc[3][1] += a3 * b.y; acc[3][2] += a3 * b.z; acc[3][3] += a3 * b.w;
    }

#pragma unroll
    for (int i = 0; i < 4; ++i) {
        float4 v = make_float4(acc[i][0], acc[i][1], acc[i][2], acc[i][3]);
        *(float4*)&H[(size_t)(row0 + r0 + i) * EMB + c0] = v;
    }
}

// ---------------- out = dinv^2 * h + b ----------------

__global__ void init_out_kernel(const float* __restrict__ H,
                                const float* __restrict__ dinv,
                                const float* __restrict__ bias,
                                float* __restrict__ out) {
    int i = blockIdx.x * blockDim.x + threadIdx.x;   // over N*32 float4s
    if (i >= N_NODES * (EMB / 4)) return;
    int n  = i / 32;
    int c4 = (i % 32) * 4;
    float di = dinv[n];
    float s  = di * di;
    float4 h = *(const float4*)&H[(size_t)i * 4];
    float4 b = *(const float4*)&bias[c4];
    float4 r;
    r.x = s * h.x + b.x;
    r.y = s * h.y + b.y;
    r.z = s * h.z + b.z;
    r.w = s * h.w + b.w;
    *(float4*)&out[(size_t)i * 4] = r;
}

// ---------------- edge scatter: out[dst] += dinv[src]*dinv[dst]*h[src] ----------------
// one wave (64 lanes) per edge; each lane handles 2 consecutive dims.

__global__ void scatter_kernel(const int* __restrict__ pos_src, const int* __restrict__ pos_dst,
                               const int* __restrict__ neg_src, const int* __restrict__ neg_dst,
                               const float* __restrict__ H, const float* __restrict__ dinv,
                               float* __restrict__ out) {
    int gtid   = blockIdx.x * blockDim.x + threadIdx.x;
    int wave   = gtid >> 6;
    int lane   = threadIdx.x & 63;
    int nwaves = (gridDim.x * blockDim.x) >> 6;

    for (int e = wave; e < 2 * NE; e += nwaves) {
        int s, d;
        if (e < NE) { s = pos_src[e]; d = pos_dst[e]; }
        else        { s = neg_src[e - NE]; d = neg_dst[e - NE]; }
        float norm = dinv[s] * dinv[d];
        float2 h = *(const float2*)&H[(size_t)s * EMB + lane * 2];
        float* o = &out[(size_t)d * EMB + lane * 2];
        atomicAdd(o + 0, norm * h.x);
        atomicAdd(o + 1, norm * h.y);
    }
}

// ---------------- launch ----------------

extern "C" void kernel_launch(void* const* d_in, const int* in_sizes, int n_in,
                              void* d_out, int out_size, void* d_ws, size_t ws_size,
                              hipStream_t stream) {
    const float* x  = (const float*)d_in[0];
    const float* W0 = (const float*)d_in[1];
    const float* b0 = (const float*)d_in[2];
    const float* W1 = (const float*)d_in[3];
    const float* b1 = (const float*)d_in[4];
    const int*   pos = (const int*)d_in[5];
    const int*   neg = (const int*)d_in[6];
    float* out = (float*)d_out;

    float* ws   = (float*)d_ws;
    float* dinv = ws;                 // N_NODES floats (deg -> dinv in place)
    float* h    = ws + 100352;        // N_NODES*EMB floats, 16B-aligned offset

    const int* pos_src = pos;
    const int* pos_dst = pos + NE;
    const int* neg_src = neg;
    const int* neg_dst = neg + NE;

    const int nElem4 = N_NODES * (EMB / 4);

    // degrees -> dinv
    zero_f32_kernel<<<(N_NODES + 255) / 256, 256, 0, stream>>>(dinv, N_NODES);
    deg_kernel<<<(2 * NE + 255) / 256, 256, 0, stream>>>(pos_dst, neg_dst, dinv);
    dinv_kernel<<<(N_NODES + 255) / 256, 256, 0, stream>>>(dinv);

    // ---- layer 0: z0 -> out ----
    gemm_kernel<<<N_NODES / TR, 256, 0, stream>>>(x, W0, h);
    init_out_kernel<<<(nElem4 + 255) / 256, 256, 0, stream>>>(h, dinv, b0, out);
    scatter_kernel<<<4096, 256, 0, stream>>>(pos_src, pos_dst, neg_src, neg_dst, h, dinv, out);

    // ---- layer 1: z1 -> out ----
    gemm_kernel<<<N_NODES / TR, 256, 0, stream>>>(out, W1, h);
    init_out_kernel<<<(nElem4 + 255) / 256, 256, 0, stream>>>(h, dinv, b1, out);
    scatter_kernel<<<4096, 256, 0, stream>>>(pos_src, pos_dst, neg_src, neg_dst, h, dinv, out);
}

// Round 2
// 688.542 us; speedup vs baseline: 4.3095x; 4.3095x over previous
//
#include <hip/hip_runtime.h>

#define N_NODES 100000
#define EMB 128
#define NE 800000            // edges per edge set (pos / neg)
#define NEDGES (2 * NE)      // total edges
#define SCAN_ELEMS 1024
#define SCAN_BLOCKS ((N_NODES + SCAN_ELEMS - 1) / SCAN_ELEMS)   // 98

// ---------------- utility ----------------

__global__ void zero_i32_kernel(int* __restrict__ p, int n) {
    int i = blockIdx.x * blockDim.x + threadIdx.x;
    if (i < n) p[i] = 0;
}

// ---------------- CSR build ----------------

__global__ void count_kernel(const int* __restrict__ pos_dst,
                             const int* __restrict__ neg_dst,
                             int* __restrict__ cnt) {
    int i = blockIdx.x * blockDim.x + threadIdx.x;
    if (i < NEDGES) {
        int d = (i < NE) ? pos_dst[i] : neg_dst[i - NE];
        atomicAdd(&cnt[d], 1);
    }
}

// block-level exclusive scan, 1024 elems / block (256 thr x 4)
__global__ __launch_bounds__(256) void scan1_kernel(const int* __restrict__ cnt,
                                                    int* __restrict__ rowtmp,
                                                    int* __restrict__ partials) {
    __shared__ int sums[256];
    const int tid  = threadIdx.x;
    const int idx  = blockIdx.x * SCAN_ELEMS + tid * 4;

    int v[4];
    int tsum = 0;
#pragma unroll
    for (int j = 0; j < 4; ++j) {
        int id = idx + j;
        v[j] = (id < N_NODES) ? cnt[id] : 0;
        tsum += v[j];
    }
    sums[tid] = tsum;
    __syncthreads();

    int val = tsum;
    for (int off = 1; off < 256; off <<= 1) {
        int t = (tid >= off) ? sums[tid - off] : 0;
        __syncthreads();
        val += t;
        sums[tid] = val;
        __syncthreads();
    }

    int p = val - tsum;   // exclusive offset for this thread
#pragma unroll
    for (int j = 0; j < 4; ++j) {
        int id = idx + j;
        if (id < N_NODES) rowtmp[id] = p;
        p += v[j];
    }
    if (tid == 255) partials[blockIdx.x] = val;
}

__global__ void scan2_kernel(const int* __restrict__ partials, int* __restrict__ offs) {
    if (threadIdx.x == 0 && blockIdx.x == 0) {
        int run = 0;
        for (int i = 0; i < SCAN_BLOCKS; ++i) { offs[i] = run; run += partials[i]; }
    }
}

__global__ __launch_bounds__(256) void scan3_kernel(const int* __restrict__ rowtmp,
                                                    const int* __restrict__ offs,
                                                    const int* __restrict__ cnt,
                                                    int* __restrict__ rowptr,
                                                    int* __restrict__ cursor,
                                                    float* __restrict__ dinv) {
    const int off = offs[blockIdx.x];
#pragma unroll
    for (int j = 0; j < 4; ++j) {
        int id = blockIdx.x * SCAN_ELEMS + threadIdx.x + j * 256;
        if (id < N_NODES) {
            int r = rowtmp[id] + off;
            rowptr[id] = r;
            cursor[id] = r;
            dinv[id]   = rsqrtf((float)cnt[id] + 1.0f);  // +1 self-loop
        }
    }
    if (blockIdx.x == 0 && threadIdx.x == 0) rowptr[N_NODES] = NEDGES;
}

__global__ void fill_kernel(const int* __restrict__ pos, const int* __restrict__ neg,
                            int* __restrict__ cursor, int* __restrict__ colidx) {
    int i = blockIdx.x * blockDim.x + threadIdx.x;
    if (i < NEDGES) {
        int s, d;
        if (i < NE) { s = pos[i];      d = pos[i + NE]; }
        else        { s = neg[i - NE]; d = neg[i - NE + NE]; }
        int p = atomicAdd(&cursor[d], 1);
        colidx[p] = s;
    }
}

// ---------------- GEMM: H = X @ W  (X: [N,128], W: [128,128]) ----------------

#define TR 32

__global__ __launch_bounds__(256) void gemm_kernel(const float* __restrict__ X,
                                                   const float* __restrict__ W,
                                                   float* __restrict__ H) {
    __shared__ float Wl[128 * 128];
    __shared__ float Xt[128][TR + 1];

    const int tid  = threadIdx.x;
    const int row0 = blockIdx.x * TR;

    for (int i = tid * 4; i < 128 * 128; i += 256 * 4) {
        *(float4*)&Wl[i] = *(const float4*)&W[i];
    }
    for (int i = tid; i < TR * 128 / 4; i += 256) {
        int r  = i / 32;
        int k4 = (i % 32) * 4;
        float4 v = *(const float4*)&X[(size_t)(row0 + r) * EMB + k4];
        Xt[k4 + 0][r] = v.x;
        Xt[k4 + 1][r] = v.y;
        Xt[k4 + 2][r] = v.z;
        Xt[k4 + 3][r] = v.w;
    }
    __syncthreads();

    const int c0 = (tid % 32) * 4;
    const int r0 = (tid / 32) * 4;

    float acc[4][4];
#pragma unroll
    for (int i = 0; i < 4; ++i)
#pragma unroll
        for (int j = 0; j < 4; ++j) acc[i][j] = 0.0f;

#pragma unroll 8
    for (int k = 0; k < 128; ++k) {
        float4 b = *(float4*)&Wl[k * 128 + c0];
        float a0 = Xt[k][r0 + 0];
        float a1 = Xt[k][r0 + 1];
        float a2 = Xt[k][r0 + 2];
        float a3 = Xt[k][r0 + 3];
        acc[0][0] += a0 * b.x; acc[0][1] += a0 * b.y; acc[0][2] += a0 * b.z; acc[0][3] += a0 * b.w;
        acc[1][0] += a1 * b.x; acc[1][1] += a1 * b.y; acc[1][2] += a1 * b.z; acc[1][3] += a1 * b.w;
        acc[2][0] += a2 * b.x; acc[2][1] += a2 * b.y; acc[2][2] += a2 * b.z; acc[2][3] += a2 * b.w;
        acc[3][0] += a3 * b.x; acc[3][1] += a3 * b.y; acc[3][2] += a3 * b.z; acc[3][3] += a3 * b.w;
    }

#pragma unroll
    for (int i = 0; i < 4; ++i) {
        float4 v = make_float4(acc[i][0], acc[i][1], acc[i][2], acc[i][3]);
        *(float4*)&H[(size_t)(row0 + r0 + i) * EMB + c0] = v;
    }
}

// ---------------- fused aggregate: out[n] = sum_{e in CSR[n]} norm*h[src] + dinv^2*h[n] + b ----
// one wave per node, lane covers 2 dims; edge loop unrolled x4 for MLP.

#define AGG_WAVES 4

__global__ __launch_bounds__(256) void aggregate_kernel(const int* __restrict__ rowptr,
                                                        const int* __restrict__ colidx,
                                                        const float* __restrict__ H,
                                                        const float* __restrict__ dinv,
                                                        const float* __restrict__ bias,
                                                        float* __restrict__ out) {
    const int wave = threadIdx.x >> 6;
    const int lane = threadIdx.x & 63;
    const int node = blockIdx.x * AGG_WAVES + wave;
    if (node >= N_NODES) return;

    const int start = rowptr[node];
    const int end   = rowptr[node + 1];
    const float dd  = dinv[node];
    const int c     = lane * 2;

    float2 hs = *(const float2*)&H[(size_t)node * EMB + c];
    float2 b2 = *(const float2*)&bias[c];
    const float s2 = dd * dd;
    float accx = s2 * hs.x + b2.x;
    float accy = s2 * hs.y + b2.y;

    int e = start;
    for (; e + 4 <= end; e += 4) {
        int n0 = colidx[e + 0];
        int n1 = colidx[e + 1];
        int n2 = colidx[e + 2];
        int n3 = colidx[e + 3];
        float w0 = dinv[n0] * dd;
        float w1 = dinv[n1] * dd;
        float w2 = dinv[n2] * dd;
        float w3 = dinv[n3] * dd;
        float2 h0 = *(const float2*)&H[(size_t)n0 * EMB + c];
        float2 h1 = *(const float2*)&H[(size_t)n1 * EMB + c];
        float2 h2 = *(const float2*)&H[(size_t)n2 * EMB + c];
        float2 h3 = *(const float2*)&H[(size_t)n3 * EMB + c];
        accx += w0 * h0.x; accy += w0 * h0.y;
        accx += w1 * h1.x; accy += w1 * h1.y;
        accx += w2 * h2.x; accy += w2 * h2.y;
        accx += w3 * h3.x; accy += w3 * h3.y;
    }
    for (; e < end; ++e) {
        int n0 = colidx[e];
        float w0 = dinv[n0] * dd;
        float2 h0 = *(const float2*)&H[(size_t)n0 * EMB + c];
        accx += w0 * h0.x; accy += w0 * h0.y;
    }

    *(float2*)&out[(size_t)node * EMB + c] = make_float2(accx, accy);
}

// ---------------- launch ----------------

extern "C" void kernel_launch(void* const* d_in, const int* in_sizes, int n_in,
                              void* d_out, int out_size, void* d_ws, size_t ws_size,
                              hipStream_t stream) {
    const float* x  = (const float*)d_in[0];
    const float* W0 = (const float*)d_in[1];
    const float* b0 = (const float*)d_in[2];
    const float* W1 = (const float*)d_in[3];
    const float* b1 = (const float*)d_in[4];
    const int*   pos = (const int*)d_in[5];
    const int*   neg = (const int*)d_in[6];
    float* out = (float*)d_out;

    // workspace layout (4-byte units)
    float* ws    = (float*)d_ws;
    float* dinv  = ws;                              // 100000 f
    float* h     = ws + 100352;                     // 12.8M f
    int*   cnt     = (int*)(ws + 12900352);         // 100000
    int*   rowtmp  = (int*)(ws + 13000352);         // 100000
    int*   rowptr  = (int*)(ws + 13100704);         // 100001
    int*   cursor  = (int*)(ws + 13200708);         // 100000
    int*   partials= (int*)(ws + 13300708);         // 98
    int*   offs    = (int*)(ws + 13300808);         // 98
    int*   colidx  = (int*)(ws + 13300908);         // 1.6M

    const int* pos_dst = pos + NE;
    const int* neg_dst = neg + NE;

    // ---- CSR build (shared by both layers) ----
    zero_i32_kernel<<<(N_NODES + 255) / 256, 256, 0, stream>>>(cnt, N_NODES);
    count_kernel<<<(NEDGES + 255) / 256, 256, 0, stream>>>(pos_dst, neg_dst, cnt);
    scan1_kernel<<<SCAN_BLOCKS, 256, 0, stream>>>(cnt, rowtmp, partials);
    scan2_kernel<<<1, 64, 0, stream>>>(partials, offs);
    scan3_kernel<<<SCAN_BLOCKS, 256, 0, stream>>>(rowtmp, offs, cnt, rowptr, cursor, dinv);
    fill_kernel<<<(NEDGES + 255) / 256, 256, 0, stream>>>(pos, neg, cursor, colidx);

    // ---- layer 0 ----
    gemm_kernel<<<N_NODES / TR, 256, 0, stream>>>(x, W0, h);
    aggregate_kernel<<<N_NODES / AGG_WAVES, 256, 0, stream>>>(rowptr, colidx, h, dinv, b0, out);

    // ---- layer 1 ----
    gemm_kernel<<<N_NODES / TR, 256, 0, stream>>>(out, W1, h);
    aggregate_kernel<<<N_NODES / AGG_WAVES, 256, 0, stream>>>(rowptr, colidx, h, dinv, b1, out);
}

// Round 3
// 579.944 us; speedup vs baseline: 5.1165x; 1.1873x over previous
//
#include <hip/hip_runtime.h>

#define N_NODES 100000
#define EMB 128
#define NE 800000            // edges per edge set (pos / neg)
#define NEDGES (2 * NE)      // total edges
#define SCAN_ELEMS 1024
#define SCAN_BLOCKS ((N_NODES + SCAN_ELEMS - 1) / SCAN_ELEMS)   // 98

// ---------------- utility ----------------

__global__ void zero_i32_kernel(int* __restrict__ p, int n) {
    int i = blockIdx.x * blockDim.x + threadIdx.x;
    if (i < n) p[i] = 0;
}

// ---------------- CSR build ----------------

__global__ void count_kernel(const int* __restrict__ pos_dst,
                             const int* __restrict__ neg_dst,
                             int* __restrict__ cnt) {
    int i = blockIdx.x * blockDim.x + threadIdx.x;
    if (i < NEDGES) {
        int d = (i < NE) ? pos_dst[i] : neg_dst[i - NE];
        atomicAdd(&cnt[d], 1);
    }
}

// block-level exclusive scan, 1024 elems / block (256 thr x 4)
__global__ __launch_bounds__(256) void scan1_kernel(const int* __restrict__ cnt,
                                                    int* __restrict__ rowtmp,
                                                    int* __restrict__ partials) {
    __shared__ int sums[256];
    const int tid  = threadIdx.x;
    const int idx  = blockIdx.x * SCAN_ELEMS + tid * 4;

    int v[4];
    int tsum = 0;
#pragma unroll
    for (int j = 0; j < 4; ++j) {
        int id = idx + j;
        v[j] = (id < N_NODES) ? cnt[id] : 0;
        tsum += v[j];
    }
    sums[tid] = tsum;
    __syncthreads();

    int val = tsum;
    for (int off = 1; off < 256; off <<= 1) {
        int t = (tid >= off) ? sums[tid - off] : 0;
        __syncthreads();
        val += t;
        sums[tid] = val;
        __syncthreads();
    }

    int p = val - tsum;   // exclusive offset for this thread
#pragma unroll
    for (int j = 0; j < 4; ++j) {
        int id = idx + j;
        if (id < N_NODES) rowtmp[id] = p;
        p += v[j];
    }
    if (tid == 255) partials[blockIdx.x] = val;
}

__global__ void scan2_kernel(const int* __restrict__ partials, int* __restrict__ offs) {
    if (threadIdx.x == 0 && blockIdx.x == 0) {
        int run = 0;
        for (int i = 0; i < SCAN_BLOCKS; ++i) { offs[i] = run; run += partials[i]; }
    }
}

__global__ __launch_bounds__(256) void scan3_kernel(const int* __restrict__ rowtmp,
                                                    const int* __restrict__ offs,
                                                    const int* __restrict__ cnt,
                                                    int* __restrict__ rowptr,
                                                    int* __restrict__ cursor,
                                                    float* __restrict__ dinv) {
    const int off = offs[blockIdx.x];
#pragma unroll
    for (int j = 0; j < 4; ++j) {
        int id = blockIdx.x * SCAN_ELEMS + threadIdx.x + j * 256;
        if (id < N_NODES) {
            int r = rowtmp[id] + off;
            rowptr[id] = r;
            cursor[id] = r;
            dinv[id]   = rsqrtf((float)cnt[id] + 1.0f);  // +1 self-loop
        }
    }
    if (blockIdx.x == 0 && threadIdx.x == 0) rowptr[N_NODES] = NEDGES;
}

__global__ void fill_kernel(const int* __restrict__ pos, const int* __restrict__ neg,
                            int* __restrict__ cursor, int* __restrict__ colidx) {
    int i = blockIdx.x * blockDim.x + threadIdx.x;
    if (i < NEDGES) {
        int s, d;
        if (i < NE) { s = pos[i];      d = pos[i + NE]; }
        else        { s = neg[i - NE]; d = neg[i - NE + NE]; }
        int p = atomicAdd(&cursor[d], 1);
        __builtin_nontemporal_store(s, &colidx[p]);
    }
}

// ---------------- GEMM: H = X @ W  (X: [N,128], W: [128,128]) ----------------
// 32 rows/block, 256 threads, X tile in LDS (17 KB -> high occupancy),
// W rows read straight from global (L1/L2 broadcast across blocks).

#define TR 32

__global__ __launch_bounds__(256) void gemm_kernel(const float* __restrict__ X,
                                                   const float* __restrict__ W,
                                                   float* __restrict__ H) {
    __shared__ float Xr[TR][EMB + 4];    // 32 x 132 floats = 16.9 KiB

    const int tid  = threadIdx.x;
    const int row0 = blockIdx.x * TR;

    // stage X tile: 32 rows x 32 float4
    for (int i = tid; i < TR * (EMB / 4); i += 256) {
        int r  = i >> 5;
        int k4 = (i & 31) << 2;
        *(float4*)&Xr[r][k4] = *(const float4*)&X[(size_t)(row0 + r) * EMB + k4];
    }
    __syncthreads();

    const int c0 = (tid & 31) * 4;   // output col group
    const int r0 = (tid >> 5) * 4;   // output row group (within tile)

    float acc[4][4];
#pragma unroll
    for (int i = 0; i < 4; ++i)
#pragma unroll
        for (int j = 0; j < 4; ++j) acc[i][j] = 0.0f;

#pragma unroll 2
    for (int k4 = 0; k4 < EMB; k4 += 4) {
        float4 xa0 = *(float4*)&Xr[r0 + 0][k4];
        float4 xa1 = *(float4*)&Xr[r0 + 1][k4];
        float4 xa2 = *(float4*)&Xr[r0 + 2][k4];
        float4 xa3 = *(float4*)&Xr[r0 + 3][k4];
#pragma unroll
        for (int j = 0; j < 4; ++j) {
            float4 w = *(const float4*)&W[(size_t)(k4 + j) * EMB + c0];
            float a0 = (j == 0) ? xa0.x : (j == 1) ? xa0.y : (j == 2) ? xa0.z : xa0.w;
            float a1 = (j == 0) ? xa1.x : (j == 1) ? xa1.y : (j == 2) ? xa1.z : xa1.w;
            float a2 = (j == 0) ? xa2.x : (j == 1) ? xa2.y : (j == 2) ? xa2.z : xa2.w;
            float a3 = (j == 0) ? xa3.x : (j == 1) ? xa3.y : (j == 2) ? xa3.z : xa3.w;
            acc[0][0] += a0 * w.x; acc[0][1] += a0 * w.y; acc[0][2] += a0 * w.z; acc[0][3] += a0 * w.w;
            acc[1][0] += a1 * w.x; acc[1][1] += a1 * w.y; acc[1][2] += a1 * w.z; acc[1][3] += a1 * w.w;
            acc[2][0] += a2 * w.x; acc[2][1] += a2 * w.y; acc[2][2] += a2 * w.z; acc[2][3] += a2 * w.w;
            acc[3][0] += a3 * w.x; acc[3][1] += a3 * w.y; acc[3][2] += a3 * w.z; acc[3][3] += a3 * w.w;
        }
    }

#pragma unroll
    for (int i = 0; i < 4; ++i) {
        float4 v = make_float4(acc[i][0], acc[i][1], acc[i][2], acc[i][3]);
        *(float4*)&H[(size_t)(row0 + r0 + i) * EMB + c0] = v;
    }
}

// ---------------- fused aggregate: out[n] = sum_{e in CSR[n]} norm*h[src] + dinv^2*h[n] + b ----
// one wave per node, lane covers 2 dims; edge loop unrolled x4 for MLP.

#define AGG_WAVES 4

__global__ __launch_bounds__(256) void aggregate_kernel(const int* __restrict__ rowptr,
                                                        const int* __restrict__ colidx,
                                                        const float* __restrict__ H,
                                                        const float* __restrict__ dinv,
                                                        const float* __restrict__ bias,
                                                        float* __restrict__ out) {
    const int wave = threadIdx.x >> 6;
    const int lane = threadIdx.x & 63;
    const int node = blockIdx.x * AGG_WAVES + wave;
    if (node >= N_NODES) return;

    const int start = rowptr[node];
    const int end   = rowptr[node + 1];
    const float dd  = dinv[node];
    const int c     = lane * 2;

    float2 hs = *(const float2*)&H[(size_t)node * EMB + c];
    float2 b2 = *(const float2*)&bias[c];
    const float s2 = dd * dd;
    float accx = s2 * hs.x + b2.x;
    float accy = s2 * hs.y + b2.y;

    int e = start;
    for (; e + 4 <= end; e += 4) {
        int n0 = colidx[e + 0];
        int n1 = colidx[e + 1];
        int n2 = colidx[e + 2];
        int n3 = colidx[e + 3];
        float w0 = dinv[n0] * dd;
        float w1 = dinv[n1] * dd;
        float w2 = dinv[n2] * dd;
        float w3 = dinv[n3] * dd;
        float2 h0 = *(const float2*)&H[(size_t)n0 * EMB + c];
        float2 h1 = *(const float2*)&H[(size_t)n1 * EMB + c];
        float2 h2 = *(const float2*)&H[(size_t)n2 * EMB + c];
        float2 h3 = *(const float2*)&H[(size_t)n3 * EMB + c];
        accx += w0 * h0.x; accy += w0 * h0.y;
        accx += w1 * h1.x; accy += w1 * h1.y;
        accx += w2 * h2.x; accy += w2 * h2.y;
        accx += w3 * h3.x; accy += w3 * h3.y;
    }
    for (; e < end; ++e) {
        int n0 = colidx[e];
        float w0 = dinv[n0] * dd;
        float2 h0 = *(const float2*)&H[(size_t)n0 * EMB + c];
        accx += w0 * h0.x; accy += w0 * h0.y;
    }

    *(float2*)&out[(size_t)node * EMB + c] = make_float2(accx, accy);
}

// ---------------- launch ----------------

extern "C" void kernel_launch(void* const* d_in, const int* in_sizes, int n_in,
                              void* d_out, int out_size, void* d_ws, size_t ws_size,
                              hipStream_t stream) {
    const float* x  = (const float*)d_in[0];
    const float* W0 = (const float*)d_in[1];
    const float* b0 = (const float*)d_in[2];
    const float* W1 = (const float*)d_in[3];
    const float* b1 = (const float*)d_in[4];
    const int*   pos = (const int*)d_in[5];
    const int*   neg = (const int*)d_in[6];
    float* out = (float*)d_out;

    // workspace layout (4-byte units)
    float* ws    = (float*)d_ws;
    float* dinv  = ws;                              // 100000 f
    float* h     = ws + 100352;                     // 12.8M f
    int*   cnt     = (int*)(ws + 12900352);         // 100000
    int*   rowtmp  = (int*)(ws + 13000352);         // 100000
    int*   rowptr  = (int*)(ws + 13100704);         // 100001
    int*   cursor  = (int*)(ws + 13200708);         // 100000
    int*   partials= (int*)(ws + 13300708);         // 98
    int*   offs    = (int*)(ws + 13300808);         // 98
    int*   colidx  = (int*)(ws + 13300908);         // 1.6M

    const int* pos_dst = pos + NE;
    const int* neg_dst = neg + NE;

    // ---- CSR build (shared by both layers) ----
    zero_i32_kernel<<<(N_NODES + 255) / 256, 256, 0, stream>>>(cnt, N_NODES);
    count_kernel<<<(NEDGES + 255) / 256, 256, 0, stream>>>(pos_dst, neg_dst, cnt);
    scan1_kernel<<<SCAN_BLOCKS, 256, 0, stream>>>(cnt, rowtmp, partials);
    scan2_kernel<<<1, 64, 0, stream>>>(partials, offs);
    scan3_kernel<<<SCAN_BLOCKS, 256, 0, stream>>>(rowtmp, offs, cnt, rowptr, cursor, dinv);
    fill_kernel<<<(NEDGES + 255) / 256, 256, 0, stream>>>(pos, neg, cursor, colidx);

    // ---- layer 0 ----
    gemm_kernel<<<N_NODES / TR, 256, 0, stream>>>(x, W0, h);
    aggregate_kernel<<<N_NODES / AGG_WAVES, 256, 0, stream>>>(rowptr, colidx, h, dinv, b0, out);

    // ---- layer 1 ----
    gemm_kernel<<<N_NODES / TR, 256, 0, stream>>>(out, W1, h);
    aggregate_kernel<<<N_NODES / AGG_WAVES, 256, 0, stream>>>(rowptr, colidx, h, dinv, b1, out);
}

// Round 4
// 483.736 us; speedup vs baseline: 6.1341x; 1.1989x over previous
//
#include <hip/hip_runtime.h>

#define N_NODES 100000
#define EMB 128
#define NE 800000            // edges per edge set (pos / neg)
#define NEDGES (2 * NE)      // total edges
#define SCAN_ELEMS 1024
#define SCAN_BLOCKS ((N_NODES + SCAN_ELEMS - 1) / SCAN_ELEMS)   // 98

// windowed counting sort for CSR fill
#define NWIN 64
#define WNODES 1563          // 64*1563 = 100032 >= N_NODES
#define ACHUNK 8192
#define ABLOCKS ((NEDGES + ACHUNK - 1) / ACHUNK)                // 196
#define SEGCAP 28000         // per-window colidx capacity (mean 25008, +19 sigma)

// ---------------- utility ----------------

__global__ void zero_i32_kernel(int* __restrict__ p, int n) {
    int i = blockIdx.x * blockDim.x + threadIdx.x;
    if (i < n) p[i] = 0;
}

// ---------------- CSR build: degree count ----------------

__global__ void count_kernel(const int* __restrict__ pos_dst,
                             const int* __restrict__ neg_dst,
                             int* __restrict__ cnt) {
    int i = blockIdx.x * blockDim.x + threadIdx.x;
    if (i < NEDGES) {
        int d = (i < NE) ? pos_dst[i] : neg_dst[i - NE];
        atomicAdd(&cnt[d], 1);
    }
}

// block-level exclusive scan, 1024 elems / block (256 thr x 4)
__global__ __launch_bounds__(256) void scan1_kernel(const int* __restrict__ cnt,
                                                    int* __restrict__ rowtmp,
                                                    int* __restrict__ partials) {
    __shared__ int sums[256];
    const int tid  = threadIdx.x;
    const int idx  = blockIdx.x * SCAN_ELEMS + tid * 4;

    int v[4];
    int tsum = 0;
#pragma unroll
    for (int j = 0; j < 4; ++j) {
        int id = idx + j;
        v[j] = (id < N_NODES) ? cnt[id] : 0;
        tsum += v[j];
    }
    sums[tid] = tsum;
    __syncthreads();

    int val = tsum;
    for (int off = 1; off < 256; off <<= 1) {
        int t = (tid >= off) ? sums[tid - off] : 0;
        __syncthreads();
        val += t;
        sums[tid] = val;
        __syncthreads();
    }

    int p = val - tsum;
#pragma unroll
    for (int j = 0; j < 4; ++j) {
        int id = idx + j;
        if (id < N_NODES) rowtmp[id] = p;
        p += v[j];
    }
    if (tid == 255) partials[blockIdx.x] = val;
}

__global__ void scan2_kernel(const int* __restrict__ partials, int* __restrict__ offs) {
    if (threadIdx.x == 0 && blockIdx.x == 0) {
        int run = 0;
        for (int i = 0; i < SCAN_BLOCKS; ++i) { offs[i] = run; run += partials[i]; }
    }
}

__global__ __launch_bounds__(256) void scan3_kernel(const int* __restrict__ rowtmp,
                                                    const int* __restrict__ offs,
                                                    const int* __restrict__ cnt,
                                                    int* __restrict__ rowptr,
                                                    float* __restrict__ dinv) {
    const int off = offs[blockIdx.x];
#pragma unroll
    for (int j = 0; j < 4; ++j) {
        int id = blockIdx.x * SCAN_ELEMS + threadIdx.x + j * 256;
        if (id < N_NODES) {
            rowptr[id] = rowtmp[id] + off;
            dinv[id]   = rsqrtf((float)cnt[id] + 1.0f);  // +1 self-loop
        }
    }
    if (blockIdx.x == 0 && threadIdx.x == 0) rowptr[N_NODES] = NEDGES;
}

__global__ void binit_kernel(const int* __restrict__ rowptr, int* __restrict__ bucket_cursor) {
    int w = threadIdx.x;
    if (w < NWIN) {
        int lo = w * WNODES;
        bucket_cursor[w] = rowptr[(lo < N_NODES) ? lo : N_NODES];
    }
}

// ---- Phase A: bin edges by dst-window, append contiguously per window ----
// record: (d - lo) << 17 | src   (d-lo < 2048, src < 131072)

__global__ __launch_bounds__(256) void binA_kernel(const int* __restrict__ pos,
                                                   const int* __restrict__ neg,
                                                   int* __restrict__ bucket_cursor,
                                                   unsigned* __restrict__ pairs) {
    __shared__ int lcnt[NWIN];
    __shared__ int lofs[NWIN];
    __shared__ int lcur[NWIN];
    __shared__ int gbase[NWIN];
    __shared__ unsigned pbuf[ACHUNK];
    __shared__ unsigned char wbuf[ACHUNK];

    const int tid  = threadIdx.x;
    const int e0   = blockIdx.x * ACHUNK;
    const int ecnt = (NEDGES - e0 < ACHUNK) ? (NEDGES - e0) : ACHUNK;

    if (tid < NWIN) lcnt[tid] = 0;
    __syncthreads();

    // pass 1: window histogram
    for (int k = tid; k < ecnt; k += 256) {
        int i = e0 + k;
        int d = (i < NE) ? pos[NE + i] : neg[i];   // dst
        atomicAdd(&lcnt[d / WNODES], 1);
    }
    __syncthreads();

    if (tid == 0) {
        int run = 0;
        for (int w = 0; w < NWIN; ++w) { lofs[w] = run; run += lcnt[w]; }
    }
    __syncthreads();
    if (tid < NWIN) {
        lcur[tid]  = lofs[tid];
        gbase[tid] = atomicAdd(&bucket_cursor[tid], lcnt[tid]);
    }
    __syncthreads();

    // pass 2: bin into LDS
    for (int k = tid; k < ecnt; k += 256) {
        int i = e0 + k;
        int s, d;
        if (i < NE) { s = pos[i];      d = pos[NE + i]; }
        else        { s = neg[i - NE]; d = neg[i]; }
        int w = d / WNODES;
        unsigned v = ((unsigned)(d - w * WNODES) << 17) | (unsigned)s;
        int lp = atomicAdd(&lcur[w], 1);
        pbuf[lp] = v;
        wbuf[lp] = (unsigned char)w;
    }
    __syncthreads();

    // pass 3: contiguous copy-out per window
    for (int k = tid; k < ecnt; k += 256) {
        int w = wbuf[k];
        pairs[gbase[w] + (k - lofs[w])] = pbuf[k];
    }
}

// ---- Phase B: per-window LDS sort to final CSR order, sequential writeback (in place) ----

__global__ __launch_bounds__(1024) void binB_kernel(const int* __restrict__ rowptr,
                                                    unsigned* __restrict__ pairs) {
    __shared__ int colseg[SEGCAP];     // 112 KB
    __shared__ int lcur[WNODES];       // 6.1 KB

    const int w    = blockIdx.x;
    const int lo   = w * WNODES;
    const int hi   = (lo + WNODES < N_NODES) ? lo + WNODES : N_NODES;
    const int nn   = hi - lo;
    const int base = rowptr[lo];
    const int cntw = rowptr[hi] - base;
    const int tid  = threadIdx.x;

    for (int k = tid; k < nn; k += 1024) lcur[k] = rowptr[lo + k] - base;
    __syncthreads();

    for (int k = tid; k < cntw; k += 1024) {
        unsigned v = pairs[base + k];
        int dl = v >> 17;
        int s  = (int)(v & 0x1FFFFu);
        int lp = atomicAdd(&lcur[dl], 1);
        if (lp < SEGCAP) colseg[lp] = s;
    }
    __syncthreads();

    for (int k = tid; k < cntw; k += 1024) pairs[base + k] = (unsigned)colseg[k];
}

// ---------------- GEMM: H = X @ W  (X: [N,128], W: [128,128]) ----------------

#define TR 32

__global__ __launch_bounds__(256) void gemm_kernel(const float* __restrict__ X,
                                                   const float* __restrict__ W,
                                                   float* __restrict__ H) {
    __shared__ float Xr[TR][EMB + 4];    // 32 x 132 floats = 16.9 KiB

    const int tid  = threadIdx.x;
    const int row0 = blockIdx.x * TR;

    for (int i = tid; i < TR * (EMB / 4); i += 256) {
        int r  = i >> 5;
        int k4 = (i & 31) << 2;
        *(float4*)&Xr[r][k4] = *(const float4*)&X[(size_t)(row0 + r) * EMB + k4];
    }
    __syncthreads();

    const int c0 = (tid & 31) * 4;
    const int r0 = (tid >> 5) * 4;

    float acc[4][4];
#pragma unroll
    for (int i = 0; i < 4; ++i)
#pragma unroll
        for (int j = 0; j < 4; ++j) acc[i][j] = 0.0f;

#pragma unroll 2
    for (int k4 = 0; k4 < EMB; k4 += 4) {
        float4 xa0 = *(float4*)&Xr[r0 + 0][k4];
        float4 xa1 = *(float4*)&Xr[r0 + 1][k4];
        float4 xa2 = *(float4*)&Xr[r0 + 2][k4];
        float4 xa3 = *(float4*)&Xr[r0 + 3][k4];
#pragma unroll
        for (int j = 0; j < 4; ++j) {
            float4 w = *(const float4*)&W[(size_t)(k4 + j) * EMB + c0];
            float a0 = (j == 0) ? xa0.x : (j == 1) ? xa0.y : (j == 2) ? xa0.z : xa0.w;
            float a1 = (j == 0) ? xa1.x : (j == 1) ? xa1.y : (j == 2) ? xa1.z : xa1.w;
            float a2 = (j == 0) ? xa2.x : (j == 1) ? xa2.y : (j == 2) ? xa2.z : xa2.w;
            float a3 = (j == 0) ? xa3.x : (j == 1) ? xa3.y : (j == 2) ? xa3.z : xa3.w;
            acc[0][0] += a0 * w.x; acc[0][1] += a0 * w.y; acc[0][2] += a0 * w.z; acc[0][3] += a0 * w.w;
            acc[1][0] += a1 * w.x; acc[1][1] += a1 * w.y; acc[1][2] += a1 * w.z; acc[1][3] += a1 * w.w;
            acc[2][0] += a2 * w.x; acc[2][1] += a2 * w.y; acc[2][2] += a2 * w.z; acc[2][3] += a2 * w.w;
            acc[3][0] += a3 * w.x; acc[3][1] += a3 * w.y; acc[3][2] += a3 * w.z; acc[3][3] += a3 * w.w;
        }
    }

#pragma unroll
    for (int i = 0; i < 4; ++i) {
        float4 v = make_float4(acc[i][0], acc[i][1], acc[i][2], acc[i][3]);
        *(float4*)&H[(size_t)(row0 + r0 + i) * EMB + c0] = v;
    }
}

// ---------------- fused aggregate ----------------

#define AGG_WAVES 4

__global__ __launch_bounds__(256) void aggregate_kernel(const int* __restrict__ rowptr,
                                                        const int* __restrict__ colidx,
                                                        const float* __restrict__ H,
                                                        const float* __restrict__ dinv,
                                                        const float* __restrict__ bias,
                                                        float* __restrict__ out) {
    const int wave = threadIdx.x >> 6;
    const int lane = threadIdx.x & 63;
    const int node = blockIdx.x * AGG_WAVES + wave;
    if (node >= N_NODES) return;

    const int start = rowptr[node];
    const int end   = rowptr[node + 1];
    const float dd  = dinv[node];
    const int c     = lane * 2;

    float2 hs = *(const float2*)&H[(size_t)node * EMB + c];
    float2 b2 = *(const float2*)&bias[c];
    const float s2 = dd * dd;
    float accx = s2 * hs.x + b2.x;
    float accy = s2 * hs.y + b2.y;

    int e = start;
    for (; e + 4 <= end; e += 4) {
        int n0 = colidx[e + 0];
        int n1 = colidx[e + 1];
        int n2 = colidx[e + 2];
        int n3 = colidx[e + 3];
        float w0 = dinv[n0] * dd;
        float w1 = dinv[n1] * dd;
        float w2 = dinv[n2] * dd;
        float w3 = dinv[n3] * dd;
        float2 h0 = *(const float2*)&H[(size_t)n0 * EMB + c];
        float2 h1 = *(const float2*)&H[(size_t)n1 * EMB + c];
        float2 h2 = *(const float2*)&H[(size_t)n2 * EMB + c];
        float2 h3 = *(const float2*)&H[(size_t)n3 * EMB + c];
        accx += w0 * h0.x; accy += w0 * h0.y;
        accx += w1 * h1.x; accy += w1 * h1.y;
        accx += w2 * h2.x; accy += w2 * h2.y;
        accx += w3 * h3.x; accy += w3 * h3.y;
    }
    for (; e < end; ++e) {
        int n0 = colidx[e];
        float w0 = dinv[n0] * dd;
        float2 h0 = *(const float2*)&H[(size_t)n0 * EMB + c];
        accx += w0 * h0.x; accy += w0 * h0.y;
    }

    *(float2*)&out[(size_t)node * EMB + c] = make_float2(accx, accy);
}

// ---------------- launch ----------------

extern "C" void kernel_launch(void* const* d_in, const int* in_sizes, int n_in,
                              void* d_out, int out_size, void* d_ws, size_t ws_size,
                              hipStream_t stream) {
    const float* x  = (const float*)d_in[0];
    const float* W0 = (const float*)d_in[1];
    const float* b0 = (const float*)d_in[2];
    const float* W1 = (const float*)d_in[3];
    const float* b1 = (const float*)d_in[4];
    const int*   pos = (const int*)d_in[5];
    const int*   neg = (const int*)d_in[6];
    float* out = (float*)d_out;

    // workspace layout (4-byte units)
    float* ws      = (float*)d_ws;
    float* dinv    = ws;                            // 100000
    float* h       = ws + 100352;                   // 12.8M
    int*   cnt     = (int*)(ws + 12900352);         // 100000
    int*   rowtmp  = (int*)(ws + 13000352);         // 100000
    int*   rowptr  = (int*)(ws + 13100704);         // 100001
    int*   partials= (int*)(ws + 13200708);         // 98
    int*   offs    = (int*)(ws + 13200808);         // 98
    int*   bcur    = (int*)(ws + 13200908);         // 64
    int*   colidx  = (int*)(ws + 13201036);         // 1.6M (also the Phase-A pair buffer)

    const int* pos_dst = pos + NE;
    const int* neg_dst = neg + NE;

    // ---- CSR build (shared by both layers) ----
    zero_i32_kernel<<<(N_NODES + 255) / 256, 256, 0, stream>>>(cnt, N_NODES);
    count_kernel<<<(NEDGES + 255) / 256, 256, 0, stream>>>(pos_dst, neg_dst, cnt);
    scan1_kernel<<<SCAN_BLOCKS, 256, 0, stream>>>(cnt, rowtmp, partials);
    scan2_kernel<<<1, 64, 0, stream>>>(partials, offs);
    scan3_kernel<<<SCAN_BLOCKS, 256, 0, stream>>>(rowtmp, offs, cnt, rowptr, dinv);
    binit_kernel<<<1, 64, 0, stream>>>(rowptr, bcur);
    binA_kernel<<<ABLOCKS, 256, 0, stream>>>(pos, neg, bcur, (unsigned*)colidx);
    binB_kernel<<<NWIN, 1024, 0, stream>>>(rowptr, (unsigned*)colidx);

    // ---- layer 0 ----
    gemm_kernel<<<N_NODES / TR, 256, 0, stream>>>(x, W0, h);
    aggregate_kernel<<<N_NODES / AGG_WAVES, 256, 0, stream>>>(rowptr, colidx, h, dinv, b0, out);

    // ---- layer 1 ----
    gemm_kernel<<<N_NODES / TR, 256, 0, stream>>>(out, W1, h);
    aggregate_kernel<<<N_NODES / AGG_WAVES, 256, 0, stream>>>(rowptr, colidx, h, dinv, b1, out);
}

// Round 5
// 386.113 us; speedup vs baseline: 7.6850x; 1.2528x over previous
//
#include <hip/hip_runtime.h>

#define N_NODES 100000
#define EMB 128
#define NE 800000            // edges per edge set (pos / neg)
#define NEDGES (2 * NE)      // total edges
#define SCAN_ELEMS 1024
#define SCAN_BLOCKS ((N_NODES + SCAN_ELEMS - 1) / SCAN_ELEMS)   // 98

// windowed counting sort for CSR fill
#define NWIN 64
#define WNODES 1563          // 64*1563 = 100032 >= N_NODES
#define ACHUNK 8192
#define ABLOCKS ((NEDGES + ACHUNK - 1) / ACHUNK)                // 196
#define SEGCAP 28000         // per-window colidx capacity

// ---------------- utility ----------------

__global__ void zero_i32_kernel(int* __restrict__ p, int n) {
    int i = blockIdx.x * blockDim.x + threadIdx.x;
    if (i < n) p[i] = 0;
}

__device__ __forceinline__ unsigned short f2bf(float f) {
    unsigned u = __builtin_bit_cast(unsigned, f);
    u += 0x7FFFu + ((u >> 16) & 1u);          // round-to-nearest-even
    return (unsigned short)(u >> 16);
}

// ---------------- CSR build: degree count ----------------

__global__ void count_kernel(const int* __restrict__ pos_dst,
                             const int* __restrict__ neg_dst,
                             int* __restrict__ cnt) {
    int i = blockIdx.x * blockDim.x + threadIdx.x;
    if (i < NEDGES) {
        int d = (i < NE) ? pos_dst[i] : neg_dst[i - NE];
        atomicAdd(&cnt[d], 1);
    }
}

// block-level exclusive scan, 1024 elems / block (256 thr x 4)
__global__ __launch_bounds__(256) void scan1_kernel(const int* __restrict__ cnt,
                                                    int* __restrict__ rowtmp,
                                                    int* __restrict__ partials) {
    __shared__ int sums[256];
    const int tid  = threadIdx.x;
    const int idx  = blockIdx.x * SCAN_ELEMS + tid * 4;

    int v[4];
    int tsum = 0;
#pragma unroll
    for (int j = 0; j < 4; ++j) {
        int id = idx + j;
        v[j] = (id < N_NODES) ? cnt[id] : 0;
        tsum += v[j];
    }
    sums[tid] = tsum;
    __syncthreads();

    int val = tsum;
    for (int off = 1; off < 256; off <<= 1) {
        int t = (tid >= off) ? sums[tid - off] : 0;
        __syncthreads();
        val += t;
        sums[tid] = val;
        __syncthreads();
    }

    int p = val - tsum;
#pragma unroll
    for (int j = 0; j < 4; ++j) {
        int id = idx + j;
        if (id < N_NODES) rowtmp[id] = p;
        p += v[j];
    }
    if (tid == 255) partials[blockIdx.x] = val;
}

__global__ void scan2_kernel(const int* __restrict__ partials, int* __restrict__ offs) {
    if (threadIdx.x == 0 && blockIdx.x == 0) {
        int run = 0;
        for (int i = 0; i < SCAN_BLOCKS; ++i) { offs[i] = run; run += partials[i]; }
    }
}

__global__ __launch_bounds__(256) void scan3_kernel(const int* __restrict__ rowtmp,
                                                    const int* __restrict__ offs,
                                                    const int* __restrict__ cnt,
                                                    int* __restrict__ rowptr,
                                                    float* __restrict__ dinv) {
    const int off = offs[blockIdx.x];
#pragma unroll
    for (int j = 0; j < 4; ++j) {
        int id = blockIdx.x * SCAN_ELEMS + threadIdx.x + j * 256;
        if (id < N_NODES) {
            rowptr[id] = rowtmp[id] + off;
            dinv[id]   = rsqrtf((float)cnt[id] + 1.0f);  // +1 self-loop
        }
    }
    if (blockIdx.x == 0 && threadIdx.x == 0) rowptr[N_NODES] = NEDGES;
}

__global__ void binit_kernel(const int* __restrict__ rowptr, int* __restrict__ bucket_cursor) {
    int w = threadIdx.x;
    if (w < NWIN) {
        int lo = w * WNODES;
        bucket_cursor[w] = rowptr[(lo < N_NODES) ? lo : N_NODES];
    }
}

// ---- Phase A: bin edges by dst-window, append contiguously per window ----
// record: (d - lo) << 17 | src

__global__ __launch_bounds__(256) void binA_kernel(const int* __restrict__ pos,
                                                   const int* __restrict__ neg,
                                                   int* __restrict__ bucket_cursor,
                                                   unsigned* __restrict__ pairs) {
    __shared__ int lcnt[NWIN];
    __shared__ int lofs[NWIN];
    __shared__ int lcur[NWIN];
    __shared__ int gbase[NWIN];
    __shared__ unsigned pbuf[ACHUNK];
    __shared__ unsigned char wbuf[ACHUNK];

    const int tid  = threadIdx.x;
    const int e0   = blockIdx.x * ACHUNK;
    const int ecnt = (NEDGES - e0 < ACHUNK) ? (NEDGES - e0) : ACHUNK;

    if (tid < NWIN) lcnt[tid] = 0;
    __syncthreads();

    for (int k = tid; k < ecnt; k += 256) {
        int i = e0 + k;
        int d = (i < NE) ? pos[NE + i] : neg[i];
        atomicAdd(&lcnt[d / WNODES], 1);
    }
    __syncthreads();

    if (tid == 0) {
        int run = 0;
        for (int w = 0; w < NWIN; ++w) { lofs[w] = run; run += lcnt[w]; }
    }
    __syncthreads();
    if (tid < NWIN) {
        lcur[tid]  = lofs[tid];
        gbase[tid] = atomicAdd(&bucket_cursor[tid], lcnt[tid]);
    }
    __syncthreads();

    for (int k = tid; k < ecnt; k += 256) {
        int i = e0 + k;
        int s, d;
        if (i < NE) { s = pos[i];      d = pos[NE + i]; }
        else        { s = neg[i - NE]; d = neg[i]; }
        int w = d / WNODES;
        unsigned v = ((unsigned)(d - w * WNODES) << 17) | (unsigned)s;
        int lp = atomicAdd(&lcur[w], 1);
        pbuf[lp] = v;
        wbuf[lp] = (unsigned char)w;
    }
    __syncthreads();

    for (int k = tid; k < ecnt; k += 256) {
        int w = wbuf[k];
        pairs[gbase[w] + (k - lofs[w])] = pbuf[k];
    }
}

// ---- Phase B: per-window LDS sort to final CSR order, sequential writeback ----

__global__ __launch_bounds__(1024) void binB_kernel(const int* __restrict__ rowptr,
                                                    unsigned* __restrict__ pairs) {
    __shared__ int colseg[SEGCAP];     // 112 KB
    __shared__ int lcur[WNODES];       // 6.1 KB

    const int w    = blockIdx.x;
    const int lo   = w * WNODES;
    const int hi   = (lo + WNODES < N_NODES) ? lo + WNODES : N_NODES;
    const int nn   = hi - lo;
    const int base = rowptr[lo];
    const int cntw = rowptr[hi] - base;
    const int tid  = threadIdx.x;

    for (int k = tid; k < nn; k += 1024) lcur[k] = rowptr[lo + k] - base;
    __syncthreads();

    for (int k = tid; k < cntw; k += 1024) {
        unsigned v = pairs[base + k];
        int dl = v >> 17;
        int s  = (int)(v & 0x1FFFFu);
        int lp = atomicAdd(&lcur[dl], 1);
        if (lp < SEGCAP) colseg[lp] = s;
    }
    __syncthreads();

    for (int k = tid; k < cntw; k += 1024) pairs[base + k] = (unsigned)colseg[k];
}

// ---------------- GEMM: Hb(bf16) = X @ W  (X: [N,128] f32, W: [128,128] f32) ----------------

#define TR 32

__global__ __launch_bounds__(256) void gemm_kernel(const float* __restrict__ X,
                                                   const float* __restrict__ W,
                                                   unsigned short* __restrict__ Hb) {
    __shared__ float Xr[TR][EMB + 4];    // 16.9 KiB

    const int tid  = threadIdx.x;
    const int row0 = blockIdx.x * TR;

    for (int i = tid; i < TR * (EMB / 4); i += 256) {
        int r  = i >> 5;
        int k4 = (i & 31) << 2;
        *(float4*)&Xr[r][k4] = *(const float4*)&X[(size_t)(row0 + r) * EMB + k4];
    }
    __syncthreads();

    const int c0 = (tid & 31) * 4;
    const int r0 = (tid >> 5) * 4;

    float acc[4][4];
#pragma unroll
    for (int i = 0; i < 4; ++i)
#pragma unroll
        for (int j = 0; j < 4; ++j) acc[i][j] = 0.0f;

#pragma unroll 2
    for (int k4 = 0; k4 < EMB; k4 += 4) {
        float4 xa0 = *(float4*)&Xr[r0 + 0][k4];
        float4 xa1 = *(float4*)&Xr[r0 + 1][k4];
        float4 xa2 = *(float4*)&Xr[r0 + 2][k4];
        float4 xa3 = *(float4*)&Xr[r0 + 3][k4];
#pragma unroll
        for (int j = 0; j < 4; ++j) {
            float4 w = *(const float4*)&W[(size_t)(k4 + j) * EMB + c0];
            float a0 = (j == 0) ? xa0.x : (j == 1) ? xa0.y : (j == 2) ? xa0.z : xa0.w;
            float a1 = (j == 0) ? xa1.x : (j == 1) ? xa1.y : (j == 2) ? xa1.z : xa1.w;
            float a2 = (j == 0) ? xa2.x : (j == 1) ? xa2.y : (j == 2) ? xa2.z : xa2.w;
            float a3 = (j == 0) ? xa3.x : (j == 1) ? xa3.y : (j == 2) ? xa3.z : xa3.w;
            acc[0][0] += a0 * w.x; acc[0][1] += a0 * w.y; acc[0][2] += a0 * w.z; acc[0][3] += a0 * w.w;
            acc[1][0] += a1 * w.x; acc[1][1] += a1 * w.y; acc[1][2] += a1 * w.z; acc[1][3] += a1 * w.w;
            acc[2][0] += a2 * w.x; acc[2][1] += a2 * w.y; acc[2][2] += a2 * w.z; acc[2][3] += a2 * w.w;
            acc[3][0] += a3 * w.x; acc[3][1] += a3 * w.y; acc[3][2] += a3 * w.z; acc[3][3] += a3 * w.w;
        }
    }

#pragma unroll
    for (int i = 0; i < 4; ++i) {
        ushort4 v;
        v.x = f2bf(acc[i][0]);
        v.y = f2bf(acc[i][1]);
        v.z = f2bf(acc[i][2]);
        v.w = f2bf(acc[i][3]);
        *(ushort4*)&Hb[(size_t)(row0 + r0 + i) * EMB + c0] = v;
    }
}

// ---------------- fused aggregate (bf16 gather, f32 accumulate) ----------------
// out[n] = sum_e norm * hb[src] + dinv^2 * hb[n] + b

#define AGG_WAVES 4

__global__ __launch_bounds__(256) void aggregate_kernel(const int* __restrict__ rowptr,
                                                        const int* __restrict__ colidx,
                                                        const unsigned* __restrict__ Hb32,
                                                        const float* __restrict__ dinv,
                                                        const float* __restrict__ bias,
                                                        float* __restrict__ out) {
    const int wave = threadIdx.x >> 6;
    const int lane = threadIdx.x & 63;
    const int node = blockIdx.x * AGG_WAVES + wave;
    if (node >= N_NODES) return;

    const int start = rowptr[node];
    const int end   = rowptr[node + 1];
    const float dd  = dinv[node];
    const int c     = lane * 2;

    unsigned us = Hb32[(size_t)node * 64 + lane];
    float hsx = __builtin_bit_cast(float, us << 16);
    float hsy = __builtin_bit_cast(float, us & 0xFFFF0000u);
    float2 b2 = *(const float2*)&bias[c];
    const float s2 = dd * dd;
    float accx = s2 * hsx + b2.x;
    float accy = s2 * hsy + b2.y;

    int e = start;
    for (; e + 4 <= end; e += 4) {
        int n0 = colidx[e + 0];
        int n1 = colidx[e + 1];
        int n2 = colidx[e + 2];
        int n3 = colidx[e + 3];
        float w0 = dinv[n0] * dd;
        float w1 = dinv[n1] * dd;
        float w2 = dinv[n2] * dd;
        float w3 = dinv[n3] * dd;
        unsigned u0 = Hb32[(size_t)n0 * 64 + lane];
        unsigned u1 = Hb32[(size_t)n1 * 64 + lane];
        unsigned u2 = Hb32[(size_t)n2 * 64 + lane];
        unsigned u3 = Hb32[(size_t)n3 * 64 + lane];
        accx += w0 * __builtin_bit_cast(float, u0 << 16);
        accy += w0 * __builtin_bit_cast(float, u0 & 0xFFFF0000u);
        accx += w1 * __builtin_bit_cast(float, u1 << 16);
        accy += w1 * __builtin_bit_cast(float, u1 & 0xFFFF0000u);
        accx += w2 * __builtin_bit_cast(float, u2 << 16);
        accy += w2 * __builtin_bit_cast(float, u2 & 0xFFFF0000u);
        accx += w3 * __builtin_bit_cast(float, u3 << 16);
        accy += w3 * __builtin_bit_cast(float, u3 & 0xFFFF0000u);
    }
    for (; e < end; ++e) {
        int n0 = colidx[e];
        float w0 = dinv[n0] * dd;
        unsigned u0 = Hb32[(size_t)n0 * 64 + lane];
        accx += w0 * __builtin_bit_cast(float, u0 << 16);
        accy += w0 * __builtin_bit_cast(float, u0 & 0xFFFF0000u);
    }

    *(float2*)&out[(size_t)node * EMB + c] = make_float2(accx, accy);
}

// ---------------- launch ----------------

extern "C" void kernel_launch(void* const* d_in, const int* in_sizes, int n_in,
                              void* d_out, int out_size, void* d_ws, size_t ws_size,
                              hipStream_t stream) {
    const float* x  = (const float*)d_in[0];
    const float* W0 = (const float*)d_in[1];
    const float* b0 = (const float*)d_in[2];
    const float* W1 = (const float*)d_in[3];
    const float* b1 = (const float*)d_in[4];
    const int*   pos = (const int*)d_in[5];
    const int*   neg = (const int*)d_in[6];
    float* out = (float*)d_out;

    // workspace layout (4-byte units)
    float* ws      = (float*)d_ws;
    float* dinv    = ws;                            // 100000
    unsigned short* hb = (unsigned short*)(ws + 100352);  // N*128 bf16 = 6.4M f32 slots
    int*   cnt     = (int*)(ws + 6500352);          // 100000
    int*   rowtmp  = (int*)(ws + 6600352);          // 100000
    int*   rowptr  = (int*)(ws + 6700704);          // 100001
    int*   partials= (int*)(ws + 6800708);          // 98
    int*   offs    = (int*)(ws + 6800808);          // 98
    int*   bcur    = (int*)(ws + 6800908);          // 64
    int*   colidx  = (int*)(ws + 6801036);          // 1.6M (also Phase-A pair buffer)

    const int* pos_dst = pos + NE;
    const int* neg_dst = neg + NE;

    // ---- CSR build (shared by both layers) ----
    zero_i32_kernel<<<(N_NODES + 255) / 256, 256, 0, stream>>>(cnt, N_NODES);
    count_kernel<<<(NEDGES + 255) / 256, 256, 0, stream>>>(pos_dst, neg_dst, cnt);
    scan1_kernel<<<SCAN_BLOCKS, 256, 0, stream>>>(cnt, rowtmp, partials);
    scan2_kernel<<<1, 64, 0, stream>>>(partials, offs);
    scan3_kernel<<<SCAN_BLOCKS, 256, 0, stream>>>(rowtmp, offs, cnt, rowptr, dinv);
    binit_kernel<<<1, 64, 0, stream>>>(rowptr, bcur);
    binA_kernel<<<ABLOCKS, 256, 0, stream>>>(pos, neg, bcur, (unsigned*)colidx);
    binB_kernel<<<NWIN, 1024, 0, stream>>>(rowptr, (unsigned*)colidx);

    // ---- layer 0 ----
    gemm_kernel<<<N_NODES / TR, 256, 0, stream>>>(x, W0, hb);
    aggregate_kernel<<<N_NODES / AGG_WAVES, 256, 0, stream>>>(rowptr, colidx, (const unsigned*)hb, dinv, b0, out);

    // ---- layer 1 ----
    gemm_kernel<<<N_NODES / TR, 256, 0, stream>>>(out, W1, hb);
    aggregate_kernel<<<N_NODES / AGG_WAVES, 256, 0, stream>>>(rowptr, colidx, (const unsigned*)hb, dinv, b1, out);
}